// Round 4
// baseline (376.169 us; speedup 1.0000x reference)
//
#include <hip/hip_runtime.h>

// Problem: 3x3 VALID conv, NCHW fp32.
// data: [16, 64, 128, 128], weights: [128, 64, 3, 3] -> out [16, 128, 126, 126]
// R3: zero-LDS all-global conv. Evidence: R0-R2 (3 different structures,
// traffic -30%, conflicts -100%) all pinned at ~100us with Occupancy ~26% and
// every pipe <30% => latency-bound at fixed concurrency (~2 waves/SIMD, reg
// bucket 136>128). NHWC is exactly the MFMA B-fragment layout, and nhwc (32MB)
// + wt (144KB) are L2/L3-resident, so staging is pure overhead (m169 lesson).
// New conv: B and A fragments loaded directly from global, no LDS, no
// barriers, 32co x 64sp per wave (acc 32 AGPR, ~100 unified regs,
// launch_bounds(256,4) => 4 waves/SIMD = 2x occupancy).

#define BATCH 16
#define CIN   64
#define HIN   128
#define WIN   128
#define COUT  128
#define HO    126
#define WO    126

typedef short bf16x8 __attribute__((ext_vector_type(8)));
typedef float f32x4  __attribute__((ext_vector_type(4)));

__device__ __forceinline__ unsigned short f2bf(float f) {
    union { float f; unsigned int u; } v; v.f = f;
    unsigned int u = v.u;
    unsigned int r = (u + 0x7fffu + ((u >> 16) & 1u)) >> 16;
    return (unsigned short)r;
}

// ---------- Pre-pass 1: NCHW fp32 -> NHWC bf16 (unchanged from R2) ----------
__global__ __launch_bounds__(256) void t1_nchw_to_nhwc(
        const float* __restrict__ x, unsigned short* __restrict__ y) {
    __shared__ unsigned short tile[64 * 68]; // [w][ci], pad 68 keeps 8B align
    const int b = blockIdx.z, h = blockIdx.y, w0 = blockIdx.x * 64;
    const int t = threadIdx.x;

    const int wl = t & 63, ci0 = t >> 6; // ci0 in 0..3
    const float* src = x + (((size_t)b * CIN) * HIN + h) * WIN + w0 + wl;
#pragma unroll
    for (int j = 0; j < 16; j++) {
        const int ci = ci0 + j * 4;
        tile[wl * 68 + ci] = f2bf(src[(size_t)ci * (HIN * WIN)]);
    }
    __syncthreads();

    const int ci4 = (t & 15) * 4, wl2 = t >> 4; // wl2 in 0..15
#pragma unroll
    for (int j = 0; j < 4; j++) {
        const int w = wl2 + j * 16;
        ushort4 v = *(const ushort4*)&tile[w * 68 + ci4];
        *(ushort4*)&y[(((size_t)b * HIN + h) * WIN + w0 + w) * CIN + ci4] = v;
    }
}

// ---------- Pre-pass 2: weights -> [kh*3+kw][co][ci] bf16 (unchanged) ----------
__global__ __launch_bounds__(256) void t2_weights(
        const float* __restrict__ w, unsigned short* __restrict__ wt) {
    const int idx = blockIdx.x * 256 + threadIdx.x;
    if (idx < COUT * CIN * 9) {
        const int co = idx / (CIN * 9);
        const int r  = idx % (CIN * 9);
        const int ci = r / 9;
        const int k  = r % 9;
        wt[((size_t)k * COUT + co) * CIN + ci] = f2bf(w[idx]);
    }
}

// ---------- Main: zero-LDS all-global implicit-GEMM MFMA conv ----------
// grid (2 sp-halves, 126 oh, 16 b), block 256 = 4 waves.
// Wave tile: 32 co x 64 sp. Block: 128 co (4 wave-quarters) x 64 sp.
__global__ __launch_bounds__(256, 4) void conv_mfma(
        const unsigned short* __restrict__ nhwc,   // [b][h][w][ci] bf16
        const unsigned short* __restrict__ wt,     // [tap][co][ci] bf16
        float* __restrict__ out) {
    // XCD swizzle: nwg = 4032 = 8*504, bijective chunking; each XCD gets 504
    // consecutive (b,oh,half) units = 2 full batches -> L2-local inputs.
    const int raw = (blockIdx.z * 126 + blockIdx.y) * 2 + blockIdx.x;
    const int s = (raw & 7) * 504 + (raw >> 3);
    const int b = s / 252;
    const int r2 = s - b * 252;
    const int oh = r2 >> 1;
    const int w0 = (r2 & 1) * 64;

    const int tid  = threadIdx.x;
    const int lane = tid & 63, wave = tid >> 6;
    const int col  = lane & 15, quad = lane >> 4;
    const int co0  = wave * 32;

    f32x4 acc[2][4] = {};

    // Per-lane fragment bases. A: [tap][co][ci]; B: [b][h][w][ci] (NHWC is
    // exactly the B-fragment layout: 16 contiguous bytes per lane).
    const unsigned short* abase = wt + (size_t)(co0 + col) * CIN + quad * 8;
    const unsigned short* bbase = nhwc +
        ((size_t)(b * HIN + oh) * WIN + w0 + col) * CIN + quad * 8;
    // B w-index reaches w0+ni*16+col+kw <= 129 > 127: overflows into the 4KB
    // slack after nhwc (allocated below); affects only ow>=126 lanes, whose
    // results are never stored.

#pragma unroll
    for (int t = 0; t < 9; t++) {
        const int kh = t / 3, kw = t - kh * 3;
        bf16x8 aa[2][2];
#pragma unroll
        for (int mi = 0; mi < 2; mi++)
#pragma unroll
            for (int kk = 0; kk < 2; kk++)
                aa[mi][kk] = *(const bf16x8*)(abase +
                    ((size_t)t * COUT + mi * 16) * CIN + kk * 32);
        const unsigned short* bt = bbase + (size_t)(kh * WIN + kw) * CIN;
#pragma unroll
        for (int kk = 0; kk < 2; kk++) {
            bf16x8 bb[4];
#pragma unroll
            for (int ni = 0; ni < 4; ni++)
                bb[ni] = *(const bf16x8*)(bt + (size_t)ni * 16 * CIN + kk * 32);
#pragma unroll
            for (int mi = 0; mi < 2; mi++)
#pragma unroll
                for (int ni = 0; ni < 4; ni++)
                    acc[mi][ni] = __builtin_amdgcn_mfma_f32_16x16x32_bf16(
                        aa[mi][kk], bb[ni], acc[mi][ni], 0, 0, 0);
        }
    }

    // Epilogue: direct stores. C/D layout: col(N=spatial)=lane&15,
    // row(M=co)=quad*4+reg. 16-lane groups write 64B segments (1.33x write
    // amp vs rows -- measured time-neutral in R1->R2, accepted for 0 LDS).
#pragma unroll
    for (int ni = 0; ni < 4; ni++) {
        const int ow = w0 + ni * 16 + col;
        if (ow < WO) {
#pragma unroll
            for (int mi = 0; mi < 2; mi++) {
                const int co = co0 + mi * 16 + quad * 4;
                float* o = out + (((size_t)b * COUT + co) * HO + oh) * WO + ow;
#pragma unroll
                for (int r = 0; r < 4; r++)
                    o[(size_t)r * HO * WO] = acc[mi][ni][r];
            }
        }
    }
}

// ---------- Fallback: direct fp32 conv (if d_ws too small) ----------
__global__ __launch_bounds__(256) void conv_direct(
        const float* __restrict__ x, const float* __restrict__ w,
        float* __restrict__ y) {
    const int idx = blockIdx.x * 256 + threadIdx.x;
    if (idx >= BATCH * COUT * HO * WO) return;
    const int ow = idx % WO;
    int t = idx / WO;
    const int oh = t % HO; t /= HO;
    const int co = t % COUT;
    const int b  = t / COUT;
    float acc = 0.f;
    const float* xb = x + (((size_t)b * CIN) * HIN + oh) * WIN + ow;
    const float* wc = w + (size_t)co * (CIN * 9);
    for (int ci = 0; ci < CIN; ci++) {
#pragma unroll
        for (int kh = 0; kh < 3; kh++)
#pragma unroll
            for (int kw = 0; kw < 3; kw++)
                acc += xb[(size_t)ci * (HIN * WIN) + kh * WIN + kw] * wc[ci * 9 + kh * 3 + kw];
    }
    y[idx] = acc;
}

extern "C" void kernel_launch(void* const* d_in, const int* in_sizes, int n_in,
                              void* d_out, int out_size, void* d_ws, size_t ws_size,
                              hipStream_t stream) {
    const float* data    = (const float*)d_in[0];
    const float* weights = (const float*)d_in[1];
    float* out = (float*)d_out;

    const size_t nhwc_bytes = (size_t)BATCH * HIN * WIN * CIN * 2; // 32 MiB
    const size_t slack = 4096;                                      // B halo overflow pad
    const size_t wt_bytes = (size_t)9 * COUT * CIN * 2;             // 144 KiB
    const size_t need = nhwc_bytes + slack + wt_bytes;

    if (ws_size >= need) {
        unsigned short* nhwc = (unsigned short*)d_ws;
        unsigned short* wt   = (unsigned short*)((char*)d_ws + nhwc_bytes + slack);
        t1_nchw_to_nhwc<<<dim3(2, HIN, BATCH), 256, 0, stream>>>(data, nhwc);
        t2_weights<<<(COUT * CIN * 9 + 255) / 256, 256, 0, stream>>>(weights, wt);
        conv_mfma<<<dim3(2, 126, BATCH), 256, 0, stream>>>(nhwc, wt, out);
    } else {
        const int n = BATCH * COUT * HO * WO;
        conv_direct<<<(n + 255) / 256, 256, 0, stream>>>(data, weights, out);
    }
}

// Round 5
// 244.571 us; speedup vs baseline: 1.5381x; 1.5381x over previous
//
#include <hip/hip_runtime.h>

// Problem: 3x3 VALID conv, NCHW fp32.
// data: [16, 64, 128, 128], weights: [128, 64, 3, 3] -> out [16, 128, 126, 126]
// R4: all-LDS K-loop. Evidence ranking across R0-R3: the only manipulation
// that moved conv time is global-latency operand loads in the K-loop
// (R0/R1/R2 with A-from-global all ~100us; R3 with A+B-from-global 208us;
// conflicts/traffic/barriers/write-amp all proven neutral). So: remove ALL
// global loads from the K-loop. B halo staged once (proven); A tap tiles
// (16KB) DMA'd via global_load_lds into a DOUBLE BUFFER one tap ahead --
// issue-early / barrier-drain-late, latency covered by the tap's MFMAs.
// Block = 512 thr (8 waves, 32co x 64sp each) = 128co x 126ow x 1oh.

#define BATCH 16
#define CIN   64
#define HIN   128
#define WIN   128
#define COUT  128
#define HO    126
#define WO    126

typedef short bf16x8 __attribute__((ext_vector_type(8)));
typedef float f32x4  __attribute__((ext_vector_type(4)));

__device__ __forceinline__ unsigned short f2bf(float f) {
    union { float f; unsigned int u; } v; v.f = f;
    unsigned int u = v.u;
    unsigned int r = (u + 0x7fffu + ((u >> 16) & 1u)) >> 16;
    return (unsigned short)r;
}

// async global->LDS, 16B per lane. LDS dest = wave-uniform base + lane*16.
__device__ __forceinline__ void async16(const void* g, void* l) {
    __builtin_amdgcn_global_load_lds(
        (const __attribute__((address_space(1))) unsigned int*)(unsigned long long)g,
        (__attribute__((address_space(3))) unsigned int*)(unsigned long long)l,
        16, 0, 0);
}

// ---------- Pre-pass 1: NCHW fp32 -> NHWC bf16 (unchanged) ----------
__global__ __launch_bounds__(256) void t1_nchw_to_nhwc(
        const float* __restrict__ x, unsigned short* __restrict__ y) {
    __shared__ unsigned short tile[64 * 68]; // [w][ci], pad 68 keeps 8B align
    const int b = blockIdx.z, h = blockIdx.y, w0 = blockIdx.x * 64;
    const int t = threadIdx.x;

    const int wl = t & 63, ci0 = t >> 6; // ci0 in 0..3
    const float* src = x + (((size_t)b * CIN) * HIN + h) * WIN + w0 + wl;
#pragma unroll
    for (int j = 0; j < 16; j++) {
        const int ci = ci0 + j * 4;
        tile[wl * 68 + ci] = f2bf(src[(size_t)ci * (HIN * WIN)]);
    }
    __syncthreads();

    const int ci4 = (t & 15) * 4, wl2 = t >> 4; // wl2 in 0..15
#pragma unroll
    for (int j = 0; j < 4; j++) {
        const int w = wl2 + j * 16;
        ushort4 v = *(const ushort4*)&tile[w * 68 + ci4];
        *(ushort4*)&y[(((size_t)b * HIN + h) * WIN + w0 + w) * CIN + ci4] = v;
    }
}

// ---------- Pre-pass 2: weights -> [kh*3+kw][co][ci] bf16 (unchanged) ----------
__global__ __launch_bounds__(256) void t2_weights(
        const float* __restrict__ w, unsigned short* __restrict__ wt) {
    const int idx = blockIdx.x * 256 + threadIdx.x;
    if (idx < COUT * CIN * 9) {
        const int co = idx / (CIN * 9);
        const int r  = idx % (CIN * 9);
        const int ci = r / 9;
        const int k  = r % 9;
        wt[((size_t)k * COUT + co) * CIN + ci] = f2bf(w[idx]);
    }
}

// ---------- Main: all-LDS implicit-GEMM MFMA conv ----------
// grid (126, 16), block 512 = 8 waves. Wave tile: 32co x 64sp.
// LDS: halo Bs 49,408 B + A double-buffer 2x16KB = 82,176 B -> 1 block/CU.
__global__ __launch_bounds__(512, 2) void conv_mfma(
        const unsigned short* __restrict__ nhwc,   // [b][h][w][ci] bf16
        const unsigned short* __restrict__ wt,     // [tap][co][ci] bf16
        float* __restrict__ out) {
    __shared__ __align__(16) char smem[49408 + 32768];
    short* Bs = (short*)smem;                 // [386 rows][64 ci], swizzled
    short* As = (short*)(smem + 49408);       // 2 x [128 co][64 ci], swizzled

    // XCD swizzle: nwg=2016, 2016%8==0 -> bijective chunking; each XCD gets
    // 252 consecutive (b,oh) = 2 full batches -> L2-local inputs.
    const int raw = blockIdx.y * 126 + blockIdx.x;
    const int s = (raw & 7) * 252 + (raw >> 3);
    const int b = s / 126;
    const int oh = s - b * 126;

    const int tid  = threadIdx.x;
    const int lane = tid & 63, wid = tid >> 6;   // wid 0..7
    const int co0  = (wid & 3) * 32;             // 4 co groups
    const int wn   = wid >> 1 & 0;               // placeholder (unused)
    const int spn  = wid >> 2;                   // 2 spatial halves
    const int col  = lane & 15, quad = lane >> 4;
    // staging pre-swizzle: LDS linear byte L holds global byte L^((row&7)<<4),
    // rows 128 B; valid per 1KB-aligned chunk. Read side XORs the same.
    const int swl = (lane * 16) ^ ((lane >> 3) << 4);

    // Prologue: stage 48KB halo (rows oh..oh+2, contiguous NHWC) + A tap 0.
    {
        const char* src = (const char*)nhwc + (size_t)(b * HIN + oh) * (WIN * CIN * 2);
        char* dst = (char*)Bs;
#pragma unroll
        for (int i = 0; i < 6; i++) {
            const int c = wid * 6 + i;
            async16(src + c * 1024 + swl, dst + c * 1024 + lane * 16);
        }
    }
    {
        const char* srcA = (const char*)wt; // tap 0
        char* dstA = (char*)As;
#pragma unroll
        for (int i = 0; i < 2; i++) {
            const int c = wid * 2 + i;
            async16(srcA + c * 1024 + swl, dstA + c * 1024 + lane * 16);
        }
    }
    __syncthreads(); // drains vmcnt(0): halo + A0 resident

    f32x4 acc[2][4] = {};

#pragma unroll
    for (int t = 0; t < 9; t++) {
        const int kh = t / 3, kw = t - kh * 3;

        // Issue next tap's A DMA FIRST (into the other buffer); the barrier
        // at tap end drains it after ~12 ds_reads + 16 MFMAs of cover.
        if (t + 1 < 9) {
            const char* srcA = (const char*)wt + (size_t)(t + 1) * 16384;
            char* dstA = (char*)As + ((t + 1) & 1) * 16384;
#pragma unroll
            for (int i = 0; i < 2; i++) {
                const int c = wid * 2 + i;
                async16(srcA + c * 1024 + swl, dstA + c * 1024 + lane * 16);
            }
        }

        const short* At = As + (t & 1) * 8192; // shorts
#pragma unroll
        for (int kk = 0; kk < 2; kk++) {
            bf16x8 aa[2], bb[4];
#pragma unroll
            for (int mi = 0; mi < 2; mi++) {
                const int r = co0 + mi * 16 + col;
                aa[mi] = *(const bf16x8*)&At[(r * 64 + kk * 32 + quad * 8) ^ ((r & 7) << 3)];
            }
#pragma unroll
            for (int ni = 0; ni < 4; ni++) {
                const int r = kh * 128 + spn * 64 + ni * 16 + col + kw;
                bb[ni] = *(const bf16x8*)&Bs[(r * 64 + kk * 32 + quad * 8) ^ ((r & 7) << 3)];
            }
#pragma unroll
            for (int mi = 0; mi < 2; mi++)
#pragma unroll
                for (int ni = 0; ni < 4; ni++)
                    acc[mi][ni] = __builtin_amdgcn_mfma_f32_16x16x32_bf16(
                        aa[mi], bb[ni], acc[mi][ni], 0, 0, 0);
        }
        if (t + 1 < 9) __syncthreads(); // A[t+1] DMA drained; buffer handoff
        // Rows 384..385 of Bs are never staged: they feed only sp>=126 lanes,
        // whose acc columns are never stored below.
    }

    // Epilogue: direct stores (write-amp proven time-neutral in R1->R2).
    // C/D layout: col(N=spatial)=lane&15, row(M=co)=quad*4+reg.
#pragma unroll
    for (int ni = 0; ni < 4; ni++) {
        const int ow = spn * 64 + ni * 16 + col;
        if (ow < WO) {
#pragma unroll
            for (int mi = 0; mi < 2; mi++) {
                const int co = co0 + mi * 16 + quad * 4;
                float* o = out + (((size_t)b * COUT + co) * HO + oh) * WO + ow;
#pragma unroll
                for (int r = 0; r < 4; r++)
                    o[(size_t)r * HO * WO] = acc[mi][ni][r];
            }
        }
    }
}

// ---------- Fallback: direct fp32 conv (if d_ws too small) ----------
__global__ __launch_bounds__(256) void conv_direct(
        const float* __restrict__ x, const float* __restrict__ w,
        float* __restrict__ y) {
    const int idx = blockIdx.x * 256 + threadIdx.x;
    if (idx >= BATCH * COUT * HO * WO) return;
    const int ow = idx % WO;
    int t = idx / WO;
    const int oh = t % HO; t /= HO;
    const int co = t % COUT;
    const int b  = t / COUT;
    float acc = 0.f;
    const float* xb = x + (((size_t)b * CIN) * HIN + oh) * WIN + ow;
    const float* wc = w + (size_t)co * (CIN * 9);
    for (int ci = 0; ci < CIN; ci++) {
#pragma unroll
        for (int kh = 0; kh < 3; kh++)
#pragma unroll
            for (int kw = 0; kw < 3; kw++)
                acc += xb[(size_t)ci * (HIN * WIN) + kh * WIN + kw] * wc[ci * 9 + kh * 3 + kw];
    }
    y[idx] = acc;
}

extern "C" void kernel_launch(void* const* d_in, const int* in_sizes, int n_in,
                              void* d_out, int out_size, void* d_ws, size_t ws_size,
                              hipStream_t stream) {
    const float* data    = (const float*)d_in[0];
    const float* weights = (const float*)d_in[1];
    float* out = (float*)d_out;

    const size_t nhwc_bytes = (size_t)BATCH * HIN * WIN * CIN * 2; // 32 MiB
    const size_t slack = 4096;
    const size_t wt_bytes = (size_t)9 * COUT * CIN * 2;            // 144 KiB
    const size_t need = nhwc_bytes + slack + wt_bytes;

    if (ws_size >= need) {
        unsigned short* nhwc = (unsigned short*)d_ws;
        unsigned short* wt   = (unsigned short*)((char*)d_ws + nhwc_bytes + slack);
        t1_nchw_to_nhwc<<<dim3(2, HIN, BATCH), 256, 0, stream>>>(data, nhwc);
        t2_weights<<<(COUT * CIN * 9 + 255) / 256, 256, 0, stream>>>(weights, wt);
        conv_mfma<<<dim3(126, BATCH), 512, 0, stream>>>(nhwc, wt, out);
    } else {
        const int n = BATCH * COUT * HO * WO;
        conv_direct<<<(n + 255) / 256, 256, 0, stream>>>(data, weights, out);
    }
}

// Round 6
// 237.902 us; speedup vs baseline: 1.5812x; 1.0280x over previous
//
#include <hip/hip_runtime.h>

// Problem: 3x3 VALID conv, NCHW fp32.
// data: [16, 64, 128, 128], weights: [128, 64, 3, 3] -> out [16, 128, 126, 126]
// R5: single fused kernel (t1 eliminated) + 2 blocks/CU.
// Evidence: dur_us - conv_time == 164-170us constant across R0-R4 => conv~80,
// t1~30, gaps~20, harness fills ~115 (fixed). R4's all-LDS K-loop won 20us but
// ran 1 block/CU (82KB LDS) => ~8 serial blocks/CU, prologue latency exposed.
// This round: block = 128co x 63ow x 1oh; conv transposes its own 3-row halo
// (NCHW fp32 -> [row][ci] bf16, swizzled) through an LDS bounce tile; LDS =
// 26,112 (halo) + 32,768 (A dbuf) + 9,520 (bounce) = 68,400 B -> 2 blocks/CU.
// Input is L3-resident (64MB < 256MB), so per-block halo re-reads are L2/L3
// traffic overlapped with the co-resident block's MFMA phase.

#define BATCH 16
#define CIN   64
#define HIN   128
#define WIN   128
#define COUT  128
#define HO    126
#define WO    126

typedef short bf16x8 __attribute__((ext_vector_type(8)));
typedef float f32x4  __attribute__((ext_vector_type(4)));

__device__ __forceinline__ unsigned short f2bf(float f) {
    union { float f; unsigned int u; } v; v.f = f;
    unsigned int u = v.u;
    unsigned int r = (u + 0x7fffu + ((u >> 16) & 1u)) >> 16;
    return (unsigned short)r;
}

// async global->LDS, 16B per lane. LDS dest = wave-uniform base + lane*16.
__device__ __forceinline__ void async16(const void* g, void* l) {
    __builtin_amdgcn_global_load_lds(
        (const __attribute__((address_space(1))) unsigned int*)(unsigned long long)g,
        (__attribute__((address_space(3))) unsigned int*)(unsigned long long)l,
        16, 0, 0);
}

// ---------- Pre-pass: weights [co][ci][kh][kw] fp32 -> [kh*3+kw][co][ci] bf16 ----------
__global__ __launch_bounds__(256) void t2_weights(
        const float* __restrict__ w, unsigned short* __restrict__ wt) {
    const int idx = blockIdx.x * 256 + threadIdx.x;
    if (idx < COUT * CIN * 9) {
        const int co = idx / (CIN * 9);
        const int r  = idx % (CIN * 9);
        const int ci = r / 9;
        const int k  = r % 9;
        wt[((size_t)k * COUT + co) * CIN + ci] = f2bf(w[idx]);
    }
}

// ---------- Fused: NCHW transpose-in-block + all-LDS implicit-GEMM MFMA ----------
// grid (2 wtiles, 126 oh, 16 b) = 4032 blocks; block 512 = 8 waves.
// Wave tile: 32co x 32sp (4 co-groups x 2 sp-groups). Block: 128co x 63ow.
__global__ __launch_bounds__(512, 4) void conv_fused(
        const float* __restrict__ x,               // [b][ci][h][w] fp32
        const unsigned short* __restrict__ wt,     // [tap][co][ci] bf16
        float* __restrict__ out) {
    // LDS: halo [3*68 rows][64 ci] bf16 swizzled (26,112 B)
    //      + A double-buffer 2 x [128 co][64 ci] swizzled (32,768 B)
    //      + bounce tile [68 w][70 ci-stride] ushort (9,520 B) = 68,400 B.
    __shared__ __align__(16) char smem[26112 + 32768 + 9520];
    short* halo = (short*)smem;
    short* As   = (short*)(smem + 26112);
    unsigned short* tile = (unsigned short*)(smem + 26112 + 32768);

    // XCD chunking: nwg=4032=8*504 (bijective). XCD k gets contiguous s-range
    // = 2 full batches -> temporally-local 3-row reuse window in its L2.
    const int raw = (blockIdx.z * 126 + blockIdx.y) * 2 + blockIdx.x;
    const int s = (raw & 7) * 504 + (raw >> 3);
    const int b  = s / 252;
    const int r2 = s - b * 252;
    const int oh = r2 >> 1;
    const int W0 = (r2 & 1) * 64;   // ow tile base: [W0, W0+62] valid outputs

    const int tid  = threadIdx.x;
    const int lane = tid & 63, wid = tid >> 6;   // wid 0..7
    const int co0  = (wid & 3) * 32;
    const int n0   = (wid >> 2) * 32;            // spatial sub-base within tile
    const int col  = lane & 15, quad = lane >> 4;
    // global_load_lds pre-swizzle (store side), per 1KB-aligned chunk:
    // LDS linear byte L holds global byte L ^ ((row&7)<<4), rows 128 B.
    const int swl = (lane * 16) ^ ((lane >> 3) << 4);

    // Prefetch A tap 0 (16 KB DMA); drained by the first transpose barrier.
    {
        const char* srcA = (const char*)wt;
        char* dstA = (char*)As;
#pragma unroll
        for (int i = 0; i < 2; i++) {
            const int c = wid * 2 + i;
            async16(srcA + c * 1024 + swl, dstA + c * 1024 + lane * 16);
        }
    }

    // Fused transpose: 3 input rows [ci][w] fp32 -> halo [row][ci] bf16 (swz).
    for (int kh = 0; kh < 3; kh++) {
        const int h = oh + kh;  // <= 127 always
        {   // stage 1: global float4 -> bounce tile [w][ci]
            const int w4 = (tid & 15) * 4, cib = tid >> 4; // cib 0..31
#pragma unroll
            for (int j = 0; j < 2; j++) {
                const int ci = cib + 32 * j;
                f32x4 v = *(const f32x4*)&x[(((size_t)b * CIN + ci) * HIN + h) * WIN + W0 + w4];
#pragma unroll
                for (int q = 0; q < 4; q++)
                    tile[(w4 + q) * 70 + ci] = f2bf(v[q]);
            }
            // tail w=64..67 (only needed & in-bounds for W0==0)
            if (W0 == 0 && tid < 256) {
                const int w = 64 + (tid & 3), ci = tid >> 2;
                tile[w * 70 + ci] = f2bf(x[(((size_t)b * CIN + ci) * HIN + h) * WIN + w]);
            }
        }
        __syncthreads();
        {   // stage 2: bounce tile -> swizzled ds_write into halo rows
            const int ci4 = (tid & 15) * 4, wr = tid >> 4; // wr 0..31
#pragma unroll
            for (int jj = 0; jj < 3; jj++) {
                const int widx = wr + 32 * jj;
                if (jj < 2 || wr < 4) { // widx < 68
                    ushort4 v = *(const ushort4*)&tile[widx * 70 + ci4];
                    const int r = kh * 68 + widx;
                    *(ushort4*)((char*)halo + ((r * 128 + ci4 * 2) ^ ((r & 7) << 4))) = v;
                }
            }
        }
        __syncthreads(); // tile reusable next kh; after kh=2: halo complete
    }
    // For W0==64, tile w 64..67 held stale data -> halo widx 64..67 garbage;
    // those rows feed only n+kw>=64 i.e. ow>=126 lanes, never stored.

    f32x4 acc[2][2] = {};

    // All-LDS K-loop, A double-buffered one tap ahead (R4-proven).
#pragma unroll
    for (int t = 0; t < 9; t++) {
        const int kh = t / 3, kw = t - kh * 3;
        if (t + 1 < 9) {
            const char* srcA = (const char*)wt + (size_t)(t + 1) * 16384;
            char* dstA = (char*)As + ((t + 1) & 1) * 16384;
#pragma unroll
            for (int i = 0; i < 2; i++) {
                const int c = wid * 2 + i;
                async16(srcA + c * 1024 + swl, dstA + c * 1024 + lane * 16);
            }
        }
        const short* At = As + (t & 1) * 8192; // shorts
#pragma unroll
        for (int kk = 0; kk < 2; kk++) {
            bf16x8 aa[2], bb[2];
#pragma unroll
            for (int mi = 0; mi < 2; mi++) {
                const int r = co0 + mi * 16 + col;
                aa[mi] = *(const bf16x8*)&At[(r * 64 + kk * 32 + quad * 8) ^ ((r & 7) << 3)];
            }
#pragma unroll
            for (int ni = 0; ni < 2; ni++) {
                const int r = kh * 68 + n0 + ni * 16 + col + kw;
                bb[ni] = *(const bf16x8*)&halo[(r * 64 + kk * 32 + quad * 8) ^ ((r & 7) << 3)];
            }
#pragma unroll
            for (int mi = 0; mi < 2; mi++)
#pragma unroll
                for (int ni = 0; ni < 2; ni++)
                    acc[mi][ni] = __builtin_amdgcn_mfma_f32_16x16x32_bf16(
                        aa[mi], bb[ni], acc[mi][ni], 0, 0, 0);
        }
        if (t + 1 < 9) __syncthreads(); // A[t+1] drained; buffer handoff
    }

    // Epilogue: direct stores (write pattern proven time-neutral R1->R2).
    // C/D layout: col(N=spatial)=lane&15, row(M=co)=quad*4+reg.
#pragma unroll
    for (int ni = 0; ni < 2; ni++) {
        const int ow = W0 + n0 + ni * 16 + col;
        if (ow < WO) {
#pragma unroll
            for (int mi = 0; mi < 2; mi++) {
                const int co = co0 + mi * 16 + quad * 4;
                float* o = out + (((size_t)b * COUT + co) * HO + oh) * WO + ow;
#pragma unroll
                for (int r = 0; r < 4; r++)
                    o[(size_t)r * HO * WO] = acc[mi][ni][r];
            }
        }
    }
}

// ---------- Fallback: direct fp32 conv (if d_ws too small) ----------
__global__ __launch_bounds__(256) void conv_direct(
        const float* __restrict__ x, const float* __restrict__ w,
        float* __restrict__ y) {
    const int idx = blockIdx.x * 256 + threadIdx.x;
    if (idx >= BATCH * COUT * HO * WO) return;
    const int ow = idx % WO;
    int t = idx / WO;
    const int oh = t % HO; t /= HO;
    const int co = t % COUT;
    const int b  = t / COUT;
    float acc = 0.f;
    const float* xb = x + (((size_t)b * CIN) * HIN + oh) * WIN + ow;
    const float* wc = w + (size_t)co * (CIN * 9);
    for (int ci = 0; ci < CIN; ci++) {
#pragma unroll
        for (int kh = 0; kh < 3; kh++)
#pragma unroll
            for (int kw = 0; kw < 3; kw++)
                acc += xb[(size_t)ci * (HIN * WIN) + kh * WIN + kw] * wc[ci * 9 + kh * 3 + kw];
    }
    y[idx] = acc;
}

extern "C" void kernel_launch(void* const* d_in, const int* in_sizes, int n_in,
                              void* d_out, int out_size, void* d_ws, size_t ws_size,
                              hipStream_t stream) {
    const float* data    = (const float*)d_in[0];
    const float* weights = (const float*)d_in[1];
    float* out = (float*)d_out;

    const size_t wt_bytes = (size_t)9 * COUT * CIN * 2; // 144 KiB

    if (ws_size >= wt_bytes) {
        unsigned short* wt = (unsigned short*)d_ws;
        t2_weights<<<(COUT * CIN * 9 + 255) / 256, 256, 0, stream>>>(weights, wt);
        conv_fused<<<dim3(2, 126, BATCH), 512, 0, stream>>>(data, wt, out);
    } else {
        const int n = BATCH * COUT * HO * WO;
        conv_direct<<<(n + 255) / 256, 256, 0, stream>>>(data, weights, out);
    }
}

// Round 8
// 232.080 us; speedup vs baseline: 1.6209x; 1.0251x over previous
//
#include <hip/hip_runtime.h>

// Problem: 3x3 VALID conv, NCHW fp32.
// data: [16, 64, 128, 128], weights: [128, 64, 3, 3] -> out [16, 128, 126, 126]
// R7 = R5's PROVEN barriered double-buffered K-loop + R6's register-gather
// transpose. R6's barrier-free K-loop had a twin-wave race (waves sharing a
// co-slice drift >=1 tap apart -> DMA overwrites a buffer mid-read): reverted.
// Transpose: 24+8 coalesced dword loads issued up-front (ONE latency
// exposure, overlapped with tap-0 A DMA), pack bf16x8 in regs, one swizzled
// ds_write_b128 per halo row, ONE barrier (R5's bounce path: 3 exposures + 6
// barriers was +31us). LDS 26,112 + 32,768 = 58,880 B -> 2 blocks/CU.

#define BATCH 16
#define CIN   64
#define HIN   128
#define WIN   128
#define COUT  128
#define HO    126
#define WO    126

typedef short bf16x8 __attribute__((ext_vector_type(8)));
typedef float f32x4  __attribute__((ext_vector_type(4)));

__device__ __forceinline__ unsigned short f2bf(float f) {
    union { float f; unsigned int u; } v; v.f = f;
    unsigned int u = v.u;
    unsigned int r = (u + 0x7fffu + ((u >> 16) & 1u)) >> 16;
    return (unsigned short)r;
}

// async global->LDS, 16B per lane. LDS dest = wave-uniform base + lane*16.
__device__ __forceinline__ void async16(const void* g, void* l) {
    __builtin_amdgcn_global_load_lds(
        (const __attribute__((address_space(1))) unsigned int*)(unsigned long long)g,
        (__attribute__((address_space(3))) unsigned int*)(unsigned long long)l,
        16, 0, 0);
}

// ---------- Pre-pass: weights [co][ci][kh][kw] fp32 -> [kh*3+kw][co][ci] bf16 ----------
__global__ __launch_bounds__(256) void t2_weights(
        const float* __restrict__ w, unsigned short* __restrict__ wt) {
    const int idx = blockIdx.x * 256 + threadIdx.x;
    if (idx < COUT * CIN * 9) {
        const int co = idx / (CIN * 9);
        const int r  = idx % (CIN * 9);
        const int ci = r / 9;
        const int k  = r % 9;
        wt[((size_t)k * COUT + co) * CIN + ci] = f2bf(w[idx]);
    }
}

// ---------- Fused: register-gather transpose + barriered MFMA K-loop ----------
// grid (2 wtiles, 126 oh, 16 b) = 4032 blocks; block 512 = 8 waves.
// Wave tile: 32co x 32sp. Block: 128co x 63/64ow x 1oh.
__global__ __launch_bounds__(512, 4) void conv_fused(
        const float* __restrict__ x,               // [b][ci][h][w] fp32
        const unsigned short* __restrict__ wt,     // [tap][co][ci] bf16
        float* __restrict__ out) {
    // LDS: halo [3*68 rows][64 ci] bf16, swizzled (26,112 B)
    //      + A double-buffer 2 x [128 co][64 ci] swizzled (32,768 B).
    __shared__ __align__(16) char smem[26112 + 32768];
    short* halo = (short*)smem;
    short* As   = (short*)(smem + 26112);

    // XCD chunking: nwg=4032=8*504 (bijective); XCD k gets 2 full batches.
    const int raw = (blockIdx.z * 126 + blockIdx.y) * 2 + blockIdx.x;
    const int s = (raw & 7) * 504 + (raw >> 3);
    const int b  = s / 252;
    const int r2 = s - b * 252;
    const int oh = r2 >> 1;
    const int W0 = (r2 & 1) * 64;   // ow tile base

    const int tid  = threadIdx.x;
    const int lane = tid & 63, wid = tid >> 6;   // wid 0..7
    const int co0  = (wid & 3) * 32;
    const int n0   = (wid >> 2) * 32;
    const int col  = lane & 15, quad = lane >> 4;
    // global_load_lds source pre-swizzle per 1KB-aligned chunk:
    // LDS linear byte L holds global byte L ^ ((row&7)<<4), rows 128 B.
    const int swl = (lane * 16) ^ ((lane >> 3) << 4);

    // ---- Transpose loads: register gather, single latency exposure. ----
    // Main: thread = (w = tid&63, ci-octet = tid>>6); 8 dword loads per row
    // (lanes span consecutive w -> 256B coalesced), 3 rows.
    const int tw = tid & 63, oct = tid >> 6;
    float v[3][8];
    {
        const float* xb = x + ((size_t)b * CIN + oct * 8) * (HIN * WIN)
                            + (size_t)oh * WIN + W0 + tw;
#pragma unroll
        for (int kh = 0; kh < 3; kh++)
#pragma unroll
            for (int j = 0; j < 8; j++)
                v[kh][j] = xb[(size_t)j * (HIN * WIN) + kh * WIN];
    }
    // Tail rows w=64..67 (96 tasks). Valid & needed only for W0==0; for
    // W0==64 clamp to w=127 (garbage feeds only ow>=126 lanes, never stored).
    float tv[8];
    const int oct2 = tid & 7, tw2 = 64 + ((tid >> 3) & 3), tkh = tid >> 5;
    if (tid < 96) {
        int wi = W0 + tw2; if (wi > WIN - 1) wi = WIN - 1;
        const float* xb2 = x + ((size_t)b * CIN + oct2 * 8) * (HIN * WIN)
                             + (size_t)(oh + tkh) * WIN + wi;
#pragma unroll
        for (int j = 0; j < 8; j++)
            tv[j] = xb2[(size_t)j * (HIN * WIN)];
    }

    // ---- Issue A tap-0 DMA (cooperative: 16 chunks / 8 waves = 2 each);
    // overlaps with the transpose loads above; drained by the barrier. ----
    {
        const char* srcA = (const char*)wt;
        char* dstA = (char*)As;
#pragma unroll
        for (int i = 0; i < 2; i++) {
            const int c = wid * 2 + i;
            async16(srcA + c * 1024 + swl, dstA + c * 1024 + lane * 16);
        }
    }

    // ---- Pack + one swizzled ds_write_b128 per halo row. ----
#pragma unroll
    for (int kh = 0; kh < 3; kh++) {
        bf16x8 p;
#pragma unroll
        for (int j = 0; j < 8; j++) p[j] = (short)f2bf(v[kh][j]);
        const int r = kh * 68 + tw;
        *(bf16x8*)((char*)halo + ((r * 128 + oct * 16) ^ ((r & 7) << 4))) = p;
    }
    if (tid < 96) {
        bf16x8 p;
#pragma unroll
        for (int j = 0; j < 8; j++) p[j] = (short)f2bf(tv[j]);
        const int r = tkh * 68 + tw2;
        *(bf16x8*)((char*)halo + ((r * 128 + oct2 * 16) ^ ((r & 7) << 4))) = p;
    }

    __syncthreads(); // halo complete; drains vmcnt -> A tap 0 resident

    f32x4 acc[2][2] = {};

    // ---- K-loop: 9 taps, A double-buffered one ahead, barrier per tap
    // (R4/R5-proven; barrier separates all reads of a buffer from rewrite).
#pragma unroll
    for (int t = 0; t < 9; t++) {
        const int kh = t / 3, kw = t - kh * 3;
        if (t + 1 < 9) { // issue tap t+1 into the other buffer
            const char* srcA = (const char*)wt + (size_t)(t + 1) * 16384;
            char* dstA = (char*)As + ((t + 1) & 1) * 16384;
#pragma unroll
            for (int i = 0; i < 2; i++) {
                const int c = wid * 2 + i;
                async16(srcA + c * 1024 + swl, dstA + c * 1024 + lane * 16);
            }
        }
        const short* At = As + (t & 1) * 8192; // shorts
#pragma unroll
        for (int kk = 0; kk < 2; kk++) {
            bf16x8 aa[2], bb[2];
#pragma unroll
            for (int mi = 0; mi < 2; mi++) {
                const int r = co0 + mi * 16 + col;
                aa[mi] = *(const bf16x8*)&At[(r * 64 + kk * 32 + quad * 8) ^ ((r & 7) << 3)];
            }
#pragma unroll
            for (int ni = 0; ni < 2; ni++) {
                const int r = kh * 68 + n0 + ni * 16 + col + kw;
                bb[ni] = *(const bf16x8*)&halo[(r * 64 + kk * 32 + quad * 8) ^ ((r & 7) << 3)];
            }
#pragma unroll
            for (int mi = 0; mi < 2; mi++)
#pragma unroll
                for (int ni = 0; ni < 2; ni++)
                    acc[mi][ni] = __builtin_amdgcn_mfma_f32_16x16x32_bf16(
                        aa[mi], bb[ni], acc[mi][ni], 0, 0, 0);
        }
        if (t + 1 < 9) __syncthreads(); // tap t+1 DMA drained; buffer handoff
    }

    // ---- Epilogue: direct stores (proven time-neutral pattern). ----
    // C/D layout: col(N=spatial)=lane&15, row(M=co)=quad*4+reg.
#pragma unroll
    for (int ni = 0; ni < 2; ni++) {
        const int ow = W0 + n0 + ni * 16 + col;
        if (ow < WO) {
#pragma unroll
            for (int mi = 0; mi < 2; mi++) {
                const int co = co0 + mi * 16 + quad * 4;
                float* o = out + (((size_t)b * COUT + co) * HO + oh) * WO + ow;
#pragma unroll
                for (int r = 0; r < 4; r++)
                    o[(size_t)r * HO * WO] = acc[mi][ni][r];
            }
        }
    }
}

// ---------- Fallback: direct fp32 conv (if d_ws too small) ----------
__global__ __launch_bounds__(256) void conv_direct(
        const float* __restrict__ x, const float* __restrict__ w,
        float* __restrict__ y) {
    const int idx = blockIdx.x * 256 + threadIdx.x;
    if (idx >= BATCH * COUT * HO * WO) return;
    const int ow = idx % WO;
    int t = idx / WO;
    const int oh = t % HO; t /= HO;
    const int co = t % COUT;
    const int b  = t / COUT;
    float acc = 0.f;
    const float* xb = x + (((size_t)b * CIN) * HIN + oh) * WIN + ow;
    const float* wc = w + (size_t)co * (CIN * 9);
    for (int ci = 0; ci < CIN; ci++) {
#pragma unroll
        for (int kh = 0; kh < 3; kh++)
#pragma unroll
            for (int kw = 0; kw < 3; kw++)
                acc += xb[(size_t)ci * (HIN * WIN) + kh * WIN + kw] * wc[ci * 9 + kh * 3 + kw];
    }
    y[idx] = acc;
}

extern "C" void kernel_launch(void* const* d_in, const int* in_sizes, int n_in,
                              void* d_out, int out_size, void* d_ws, size_t ws_size,
                              hipStream_t stream) {
    const float* data    = (const float*)d_in[0];
    const float* weights = (const float*)d_in[1];
    float* out = (float*)d_out;

    const size_t wt_bytes = (size_t)9 * COUT * CIN * 2; // 144 KiB

    if (ws_size >= wt_bytes) {
        unsigned short* wt = (unsigned short*)d_ws;
        t2_weights<<<(COUT * CIN * 9 + 255) / 256, 256, 0, stream>>>(weights, wt);
        conv_fused<<<dim3(2, 126, BATCH), 512, 0, stream>>>(data, wt, out);
    } else {
        const int n = BATCH * COUT * HO * WO;
        conv_direct<<<(n + 255) / 256, 256, 0, stream>>>(data, weights, out);
    }
}